// Round 2
// baseline (830.788 us; speedup 1.0000x reference)
//
#include <hip/hip_runtime.h>

namespace {

constexpr int T = 32, H = 56, W = 56;
constexpr int HW = H * W;
constexpr int THW = T * HW;
constexpr int GROUPS = H * (W / 2);   // 1568 two-pixel groups per (b,c) plane-stack

template <int N> struct ic { static constexpr int value = N; };

__device__ __forceinline__ float sigm(float x) {
    // 1/(1+e^-x); fast native exp + rcp (rel err ~1e-6, threshold is 1.9e-2)
    float e = __expf(-x);
    return __builtin_amdgcn_rcpf(1.0f + e);
}

// 128-thread blocks (2 waves/wg): the wg-slot limit (~16/CU) capped 64-thread
// blocks at 16 waves/CU; 2 waves/wg doubles that ceiling. At 84 VGPRs the
// register file allows 6 waves/SIMD (24/CU) -> launch_bounds pins that.
__global__ __launch_bounds__(128, 6)
void tts_fused(const float* __restrict__ x,
               const float* __restrict__ w1, const float* __restrict__ b1,
               const float* __restrict__ w2, const float* __restrict__ b2,
               const float* __restrict__ w3, const float* __restrict__ b3,
               const float* __restrict__ wm,
               float* __restrict__ out) {
    // blockIdx.y = (b*64 + c)  -> block-uniform so weight loads stay scalar.
    // blockIdx.x * 128 + tid   -> linear 2-pixel group within the 56x56 plane.
    const int g = blockIdx.x * 128 + threadIdx.x;
    if (g >= GROUPS) return;          // no barriers anywhere -> safe early exit
    const int bc = blockIdx.y;
    const int h  = g / 28;            // 0..55
    const int wq = g - h * 28;        // 0..27
    const int w0 = wq << 1;           // 2 pixels per thread, 8B-aligned

    const float* __restrict__ xbc = x + (size_t)bc * THW;
    float* __restrict__ obc       = out + (size_t)bc * THW;
    const int c = bc & 63;
    const float* __restrict__ wa = w1 + c * 27;  // [kt*9 + kh*3 + kw]
    const float* __restrict__ wb = w2 + c * 27;
    const float* __restrict__ wc = w3 + c * 27;
    const float bias1 = b1[c], bias2 = b2[c], bias3 = b3[c];
    const float W0 = wm[0], W1 = wm[1], W2 = wm[2];
    const float goff = 0.5f * (W0 + W1 + W2);

    const bool vtop = (h >= 1), vbot = (h <= H - 2);
    const bool vl = (wq > 0), vr = (wq < 27);
    const int boff = h * W + w0;

    // register cache: 7 planes (t-3..t+3, slot = plane mod 7) x 3 rows x 4 cols (w0-1..w0+2)
    float cc[7][3][4];
    // lag-diff shift registers per pixel
    float p1[2], p2a[2], p2b[2], p3a[2], p3b[2], p3c[2];
#pragma unroll
    for (int p = 0; p < 2; ++p) {
        p1[p] = 0.f; p2a[p] = 0.f; p2b[p] = 0.f;
        p3a[p] = 0.f; p3b[p] = 0.f; p3c[p] = 0.f;
    }

    auto zero_plane = [&](auto Sc) {
        constexpr int s = decltype(Sc)::value;
#pragma unroll
        for (int r = 0; r < 3; ++r)
#pragma unroll
            for (int j = 0; j < 4; ++j) cc[s][r][j] = 0.f;
    };

    auto load_plane = [&](auto Sc, int tp) {
        constexpr int s = decltype(Sc)::value;
        const float* pp = xbc + tp * HW + boff;
#pragma unroll
        for (int r = 0; r < 3; ++r) {
            const bool vrow = (r == 0) ? vtop : ((r == 2) ? vbot : true);
            const float* rp = pp + (r - 1) * W;
            if (vrow) {
                const float2 m = *(const float2*)rp;      // aligned: offset % 2 == 0
                cc[s][r][1] = m.x; cc[s][r][2] = m.y;
                cc[s][r][0] = vl ? rp[-1] : 0.f;
                cc[s][r][3] = vr ? rp[2]  : 0.f;
            } else {
#pragma unroll
                for (int j = 0; j < 4; ++j) cc[s][r][j] = 0.f;
            }
        }
    };

    auto conv9 = [&](float (&acc)[2], auto Sc, const float* __restrict__ wp) {
        constexpr int s = decltype(Sc)::value;
#pragma unroll
        for (int r = 0; r < 3; ++r)
#pragma unroll
            for (int kw = 0; kw < 3; ++kw) {
                const float wg = wp[r * 3 + kw];
#pragma unroll
                for (int p = 0; p < 2; ++p)
                    acc[p] = fmaf(cc[s][r][p + kw], wg, acc[p]);
            }
    };

    // prologue: planes -3..-1 are zero (slots 4,5,6); planes 0..2 loaded (slots 0,1,2)
    zero_plane(ic<4>{}); zero_plane(ic<5>{}); zero_plane(ic<6>{});
    load_plane(ic<0>{}, 0); load_plane(ic<1>{}, 1); load_plane(ic<2>{}, 2);

    auto step = [&](int t, auto Uc) {   // requires t % 7 == Uc
        constexpr int u = decltype(Uc)::value;
        constexpr int snew = (u + 3) % 7;               // slot of plane t+3
        if (t + 3 < T) load_plane(ic<snew>{}, t + 3);
        else           zero_plane(ic<snew>{});

        float a1[2], a2[2], a3[2];
#pragma unroll
        for (int p = 0; p < 2; ++p) { a1[p] = bias1; a2[p] = bias2; a3[p] = bias3; }

        conv9(a1, ic<(u + 6) % 7>{}, wa);       // plane t-1
        conv9(a1, ic<u>{},           wa + 9);   // plane t
        conv9(a1, ic<(u + 1) % 7>{}, wa + 18);  // plane t+1
        conv9(a2, ic<(u + 5) % 7>{}, wb);       // plane t-2
        conv9(a2, ic<u>{},           wb + 9);   // plane t
        conv9(a2, ic<(u + 2) % 7>{}, wb + 18);  // plane t+2
        conv9(a3, ic<(u + 4) % 7>{}, wc);       // plane t-3
        conv9(a3, ic<u>{},           wc + 9);   // plane t
        conv9(a3, ic<(u + 3) % 7>{}, wc + 18);  // plane t+3 (freshly loaded) LAST

        float2 ov;
        float* ovp = (float*)&ov;
#pragma unroll
        for (int p = 0; p < 2; ++p) {
            const float y1 = a1[p], y2 = a2[p], y3 = a3[p];
            const float d1 = (t >= 1) ? y1 - p1[p]  : y1;
            const float d2 = (t >= 2) ? y2 - p2b[p] : y2;
            const float d3 = (t >= 3) ? y3 - p3c[p] : y3;
            p1[p]  = y1;
            p2b[p] = p2a[p]; p2a[p] = y2;
            p3c[p] = p3b[p]; p3b[p] = p3a[p]; p3a[p] = y3;
            const float gte = fmaf(sigm(d1), W0,
                             fmaf(sigm(d2), W1,
                             fmaf(sigm(d3), W2, -goff)));
            ovp[p] = cc[u][1][p + 1] * gte;     // x at (t,h,w0+p) from register cache
        }
        *(float2*)(obc + t * HW + boff) = ov;
    };

#pragma unroll 1
    for (int tb = 0; tb <= T - 7; tb += 7) {    // tb = 0,7,14,21  (tb % 7 == 0)
        step(tb + 0, ic<0>{}); step(tb + 1, ic<1>{}); step(tb + 2, ic<2>{});
        step(tb + 3, ic<3>{}); step(tb + 4, ic<4>{}); step(tb + 5, ic<5>{});
        step(tb + 6, ic<6>{});
    }
    // remainder: t = 28..31 (28 % 7 == 0)
    step(28, ic<0>{}); step(29, ic<1>{}); step(30, ic<2>{}); step(31, ic<3>{});
}

}  // namespace

extern "C" void kernel_launch(void* const* d_in, const int* in_sizes, int n_in,
                              void* d_out, int out_size, void* d_ws, size_t ws_size,
                              hipStream_t stream) {
    (void)in_sizes; (void)n_in; (void)d_ws; (void)ws_size; (void)out_size;
    const float* x  = (const float*)d_in[0];
    const float* w1 = (const float*)d_in[1];
    const float* b1 = (const float*)d_in[2];
    const float* w2 = (const float*)d_in[3];
    const float* b2 = (const float*)d_in[4];
    const float* w3 = (const float*)d_in[5];
    const float* b3 = (const float*)d_in[6];
    const float* wm = (const float*)d_in[7];
    float* out = (float*)d_out;

    // grid: x = ceil(1568 groups / 128) = 13, y = 256 (b,c) pairs; block: 2 waves.
    // 2-wave blocks double the wg-slot-limited wave ceiling vs 1-wave blocks;
    // bc in blockIdx.y keeps weight/bias loads block-uniform -> scalar path.
    tts_fused<<<dim3((GROUPS + 127) / 128, 256), dim3(128), 0, stream>>>(
        x, w1, b1, w2, b2, w3, b3, wm, out);
}

// Round 3
// 615.972 us; speedup vs baseline: 1.3487x; 1.3487x over previous
//
#include <hip/hip_runtime.h>

namespace {

constexpr int T = 32, H = 56, W = 56;
constexpr int HW = H * W;
constexpr int THW = T * HW;
constexpr int GROUPS = H * (W / 2);   // 1568 two-pixel groups per (b,c) plane-stack

template <int N> struct ic { static constexpr int value = N; };

__device__ __forceinline__ float sigm(float x) {
    // 1/(1+e^-x); fast native exp + rcp (rel err ~1e-6, threshold is 1.9e-2)
    float e = __expf(-x);
    return __builtin_amdgcn_rcpf(1.0f + e);
}

// 128-thread blocks (2 waves/wg) to beat the wg-slot occupancy cap seen with
// 1-wave blocks. min-waves=5 -> VGPR budget 512/5=102 > the 84 this kernel
// needs, so NO spill (launch_bounds(128,6) squeezed to 80 and spilled the
// 84-float plane cache to scratch: 2 GB of scratch traffic, 733 us. Never 6.)
__global__ __launch_bounds__(128, 5)
void tts_fused(const float* __restrict__ x,
               const float* __restrict__ w1, const float* __restrict__ b1,
               const float* __restrict__ w2, const float* __restrict__ b2,
               const float* __restrict__ w3, const float* __restrict__ b3,
               const float* __restrict__ wm,
               float* __restrict__ out) {
    // blockIdx.y = (b*64 + c)  -> block-uniform so weight loads stay scalar.
    // blockIdx.x * 128 + tid   -> linear 2-pixel group within the 56x56 plane.
    const int g = blockIdx.x * 128 + threadIdx.x;
    if (g >= GROUPS) return;          // no barriers anywhere -> safe early exit
    const int bc = blockIdx.y;
    const int h  = g / 28;            // 0..55
    const int wq = g - h * 28;        // 0..27
    const int w0 = wq << 1;           // 2 pixels per thread, 8B-aligned

    const float* __restrict__ xbc = x + (size_t)bc * THW;
    float* __restrict__ obc       = out + (size_t)bc * THW;
    const int c = bc & 63;
    const float* __restrict__ wa = w1 + c * 27;  // [kt*9 + kh*3 + kw]
    const float* __restrict__ wb = w2 + c * 27;
    const float* __restrict__ wc = w3 + c * 27;
    const float bias1 = b1[c], bias2 = b2[c], bias3 = b3[c];
    const float W0 = wm[0], W1 = wm[1], W2 = wm[2];
    const float goff = 0.5f * (W0 + W1 + W2);

    const bool vtop = (h >= 1), vbot = (h <= H - 2);
    const bool vl = (wq > 0), vr = (wq < 27);
    const int boff = h * W + w0;

    // register cache: 7 planes (t-3..t+3, slot = plane mod 7) x 3 rows x 4 cols (w0-1..w0+2)
    float cc[7][3][4];
    // lag-diff shift registers per pixel
    float p1[2], p2a[2], p2b[2], p3a[2], p3b[2], p3c[2];
#pragma unroll
    for (int p = 0; p < 2; ++p) {
        p1[p] = 0.f; p2a[p] = 0.f; p2b[p] = 0.f;
        p3a[p] = 0.f; p3b[p] = 0.f; p3c[p] = 0.f;
    }

    auto zero_plane = [&](auto Sc) {
        constexpr int s = decltype(Sc)::value;
#pragma unroll
        for (int r = 0; r < 3; ++r)
#pragma unroll
            for (int j = 0; j < 4; ++j) cc[s][r][j] = 0.f;
    };

    auto load_plane = [&](auto Sc, int tp) {
        constexpr int s = decltype(Sc)::value;
        const float* pp = xbc + tp * HW + boff;
#pragma unroll
        for (int r = 0; r < 3; ++r) {
            const bool vrow = (r == 0) ? vtop : ((r == 2) ? vbot : true);
            const float* rp = pp + (r - 1) * W;
            if (vrow) {
                const float2 m = *(const float2*)rp;      // aligned: offset % 2 == 0
                cc[s][r][1] = m.x; cc[s][r][2] = m.y;
                cc[s][r][0] = vl ? rp[-1] : 0.f;
                cc[s][r][3] = vr ? rp[2]  : 0.f;
            } else {
#pragma unroll
                for (int j = 0; j < 4; ++j) cc[s][r][j] = 0.f;
            }
        }
    };

    auto conv9 = [&](float (&acc)[2], auto Sc, const float* __restrict__ wp) {
        constexpr int s = decltype(Sc)::value;
#pragma unroll
        for (int r = 0; r < 3; ++r)
#pragma unroll
            for (int kw = 0; kw < 3; ++kw) {
                const float wg = wp[r * 3 + kw];
#pragma unroll
                for (int p = 0; p < 2; ++p)
                    acc[p] = fmaf(cc[s][r][p + kw], wg, acc[p]);
            }
    };

    // prologue: planes -3..-1 are zero (slots 4,5,6); planes 0..2 loaded (slots 0,1,2)
    zero_plane(ic<4>{}); zero_plane(ic<5>{}); zero_plane(ic<6>{});
    load_plane(ic<0>{}, 0); load_plane(ic<1>{}, 1); load_plane(ic<2>{}, 2);

    auto step = [&](int t, auto Uc) {   // requires t % 7 == Uc
        constexpr int u = decltype(Uc)::value;
        constexpr int snew = (u + 3) % 7;               // slot of plane t+3
        if (t + 3 < T) load_plane(ic<snew>{}, t + 3);
        else           zero_plane(ic<snew>{});

        float a1[2], a2[2], a3[2];
#pragma unroll
        for (int p = 0; p < 2; ++p) { a1[p] = bias1; a2[p] = bias2; a3[p] = bias3; }

        conv9(a1, ic<(u + 6) % 7>{}, wa);       // plane t-1
        conv9(a1, ic<u>{},           wa + 9);   // plane t
        conv9(a1, ic<(u + 1) % 7>{}, wa + 18);  // plane t+1
        conv9(a2, ic<(u + 5) % 7>{}, wb);       // plane t-2
        conv9(a2, ic<u>{},           wb + 9);   // plane t
        conv9(a2, ic<(u + 2) % 7>{}, wb + 18);  // plane t+2
        conv9(a3, ic<(u + 4) % 7>{}, wc);       // plane t-3
        conv9(a3, ic<u>{},           wc + 9);   // plane t
        conv9(a3, ic<(u + 3) % 7>{}, wc + 18);  // plane t+3 (freshly loaded) LAST

        float2 ov;
        float* ovp = (float*)&ov;
#pragma unroll
        for (int p = 0; p < 2; ++p) {
            const float y1 = a1[p], y2 = a2[p], y3 = a3[p];
            const float d1 = (t >= 1) ? y1 - p1[p]  : y1;
            const float d2 = (t >= 2) ? y2 - p2b[p] : y2;
            const float d3 = (t >= 3) ? y3 - p3c[p] : y3;
            p1[p]  = y1;
            p2b[p] = p2a[p]; p2a[p] = y2;
            p3c[p] = p3b[p]; p3b[p] = p3a[p]; p3a[p] = y3;
            const float gte = fmaf(sigm(d1), W0,
                             fmaf(sigm(d2), W1,
                             fmaf(sigm(d3), W2, -goff)));
            ovp[p] = cc[u][1][p + 1] * gte;     // x at (t,h,w0+p) from register cache
        }
        *(float2*)(obc + t * HW + boff) = ov;
    };

#pragma unroll 1
    for (int tb = 0; tb <= T - 7; tb += 7) {    // tb = 0,7,14,21  (tb % 7 == 0)
        step(tb + 0, ic<0>{}); step(tb + 1, ic<1>{}); step(tb + 2, ic<2>{});
        step(tb + 3, ic<3>{}); step(tb + 4, ic<4>{}); step(tb + 5, ic<5>{});
        step(tb + 6, ic<6>{});
    }
    // remainder: t = 28..31 (28 % 7 == 0)
    step(28, ic<0>{}); step(29, ic<1>{}); step(30, ic<2>{}); step(31, ic<3>{});
}

}  // namespace

extern "C" void kernel_launch(void* const* d_in, const int* in_sizes, int n_in,
                              void* d_out, int out_size, void* d_ws, size_t ws_size,
                              hipStream_t stream) {
    (void)in_sizes; (void)n_in; (void)d_ws; (void)ws_size; (void)out_size;
    const float* x  = (const float*)d_in[0];
    const float* w1 = (const float*)d_in[1];
    const float* b1 = (const float*)d_in[2];
    const float* w2 = (const float*)d_in[3];
    const float* b2 = (const float*)d_in[4];
    const float* w3 = (const float*)d_in[5];
    const float* b3 = (const float*)d_in[6];
    const float* wm = (const float*)d_in[7];
    float* out = (float*)d_out;

    // grid: x = ceil(1568 groups / 128) = 13, y = 256 (b,c) pairs; block: 2 waves.
    // 2-wave blocks double the wg-slot-limited wave ceiling vs 1-wave blocks;
    // bc in blockIdx.y keeps weight/bias loads block-uniform -> scalar path.
    tts_fused<<<dim3((GROUPS + 127) / 128, 256), dim3(128), 0, stream>>>(
        x, w1, b1, w2, b2, w3, b3, wm, out);
}

// Round 4
// 425.670 us; speedup vs baseline: 1.9517x; 1.4471x over previous
//
#include <hip/hip_runtime.h>

namespace {

constexpr int T = 32, H = 56, W = 56;
constexpr int HW = H * W;           // 3136
constexpr int THW = T * HW;
constexpr int PLANE_B = HW * 4;     // 12544 bytes per plane
constexpr int ROW_B = W * 4;        // 224 bytes per row

template <int N> struct ic { static constexpr int value = N; };

typedef int v4i __attribute__((ext_vector_type(4)));

// CK-style direct intrinsic bindings: compiler tracks these loads (auto waitcnt),
// unlike hand-written inline asm.
__device__ float buf_load_f32(v4i srd, int voff, int soff, int aux)
    __asm("llvm.amdgcn.raw.buffer.load.f32");
__device__ void buf_store_f32(float v, v4i srd, int voff, int soff, int aux)
    __asm("llvm.amdgcn.raw.buffer.store.f32");

__device__ __forceinline__ v4i make_srd(const void* p, int nrec) {
    v4i r;
    r.x = (int)(unsigned long long)p;
    r.y = (int)((unsigned long long)p >> 32);  // stride=0 in high half
    r.z = nrec;                                // num_records = BYTES (stride 0)
    r.w = 0x00020000;                          // raw untyped dword access
    return r;
}

__device__ __forceinline__ float sigm(float x) {
    // 1/(1+e^-x); fast native exp + rcp (rel err ~1e-6, threshold is 1.9e-2)
    float e = __expf(-x);
    return __builtin_amdgcn_rcpf(1.0f + e);
}

template <int P, int N, typename F>
__device__ __forceinline__ void unroll_for(F&& f) {
    if constexpr (P < N) { f(ic<P>{}); unroll_for<P + 1, N>(f); }
}

// Streaming partial-accumulator formulation: each input plane p is loaded ONCE
// (3x3 neighborhood / thread), its 9 spatial convs scatter into pending output
// accumulators; output t emits at p = t+3. Live state ~37 floats/px vs the old
// 7-plane ring's ~105 -> fits the <=64-VGPR / 8-waves-per-SIMD occupancy bin
// (bins are power-of-2: waves halve at 64/128/256 VGPRs; R2's (128,5) pin was
// infeasible -> 800 MB scratch spill. Here true need ~47-55, cap 64 feasible.)
__global__ __launch_bounds__(256, 8)
void tts_fused(const float* __restrict__ x,
               const float* __restrict__ w1, const float* __restrict__ b1,
               const float* __restrict__ w2, const float* __restrict__ b2,
               const float* __restrict__ w3, const float* __restrict__ b3,
               const float* __restrict__ wm,
               float* __restrict__ out) {
    const int g = blockIdx.x * 256 + threadIdx.x;   // pixel index in plane
    if (g >= HW) return;                            // no barriers -> safe exit
    const int bc = blockIdx.y;                      // b*64 + c (block-uniform)
    const int h = g / W;
    const int w = g - h * W;

    const float* __restrict__ xbc = x + (size_t)bc * THW;
    float* __restrict__ obc       = out + (size_t)bc * THW;
    const int c = bc & 63;

    // weights: block-uniform addresses -> scalar loads, live in SGPRs
    float wA[27], wB[27], wC[27];
#pragma unroll
    for (int i = 0; i < 27; ++i) {
        wA[i] = w1[c * 27 + i];
        wB[i] = w2[c * 27 + i];
        wC[i] = w3[c * 27 + i];
    }
    const float bias1 = b1[c], bias2 = b2[c], bias3 = b3[c];
    const float W0 = wm[0], W1 = wm[1], W2 = wm[2];
    const float goff = 0.5f * (W0 + W1 + W2);

    // 9 loop-invariant byte offsets into the current plane. Row OOB (row<0 or
    // row>=56) is automatically out of the SRD's num_records window (unsigned
    // bounds check) -> hardware returns 0. Col OOB forced out via huge offset.
    int voff[3][3];
#pragma unroll
    for (int r = 0; r < 3; ++r)
#pragma unroll
        for (int kw = 0; kw < 3; ++kw) {
            const int row = h + r - 1, col = w + kw - 1;
            int off = row * ROW_B + col * 4;
            if ((unsigned)col >= (unsigned)W) off = 1 << 30;
            voff[r][kw] = off;
        }

    const v4i osrd = make_srd(obc, THW * 4);
    const int og4 = g * 4;

    // pending output accumulators (mod-indexed rings, all indices compile-time)
    float y1s[5], y2s[6], y3s[7];
#pragma unroll
    for (int i = 0; i < 5; ++i) y1s[i] = bias1;
#pragma unroll
    for (int i = 0; i < 6; ++i) y2s[i] = bias2;
#pragma unroll
    for (int i = 0; i < 7; ++i) y3s[i] = bias3;
    // lag-diff previous-y registers (zero-init matches "first k frames kept")
    float pv1 = 0.f, pv2[2] = {0.f, 0.f}, pv3[3] = {0.f, 0.f, 0.f};
    // 4-deep center-pixel pipeline: x[t,h,w] loaded at step t, used at step t+3
    float xc[4] = {0.f, 0.f, 0.f, 0.f};

    unroll_for<0, T + 3>([&](auto Pc) {
        constexpr int p = decltype(Pc)::value;
        if constexpr (p < T) {
            const v4i srd = make_srd(xbc + p * HW, PLANE_B);
            float v[3][3];
#pragma unroll
            for (int r = 0; r < 3; ++r)
#pragma unroll
                for (int kw = 0; kw < 3; ++kw)
                    v[r][kw] = buf_load_f32(srd, voff[r][kw], 0, 0);

            // open new output slots (old occupants emitted 1+ steps ago)
            y1s[(p + 1) % 5] = bias1;   // output t=p+1
            y2s[(p + 2) % 6] = bias2;   // output t=p+2
            y3s[(p + 3) % 7] = bias3;   // output t=p+3

            auto tap = [&](float& acc, const float* wt) {
#pragma unroll
                for (int r = 0; r < 3; ++r)
#pragma unroll
                    for (int kw = 0; kw < 3; ++kw)
                        acc = fmaf(v[r][kw], wt[r * 3 + kw], acc);
            };
            // plane p contributes: kt=0 -> t=p+dil, kt=1 -> t=p, kt=2 -> t=p-dil
            tap(y1s[(p + 1) % 5], wA + 0);      // t=p+1
            tap(y1s[p % 5],       wA + 9);      // t=p
            tap(y1s[(p + 4) % 5], wA + 18);     // t=p-1 (p=0: t=-1 -> dead slot)
            tap(y2s[(p + 2) % 6], wB + 0);      // t=p+2
            tap(y2s[p % 6],       wB + 9);      // t=p
            tap(y2s[(p + 4) % 6], wB + 18);     // t=p-2
            tap(y3s[(p + 3) % 7], wC + 0);      // t=p+3
            tap(y3s[p % 7],       wC + 9);      // t=p
            tap(y3s[(p + 4) % 7], wC + 18);     // t=p-3 (= emission slot, final add)

            xc[p % 4] = v[1][1];
        }
        if constexpr (p >= 3) {
            constexpr int t = p - 3;            // y3[t] just completed
            const float y1v = y1s[t % 5];
            const float y2v = y2s[t % 6];
            const float y3v = y3s[t % 7];
            const float d1 = y1v - pv1;          pv1 = y1v;
            const float d2 = y2v - pv2[t % 2];   pv2[t % 2] = y2v;
            const float d3 = y3v - pv3[t % 3];   pv3[t % 3] = y3v;
            const float gt = fmaf(sigm(d1), W0,
                             fmaf(sigm(d2), W1,
                             fmaf(sigm(d3), W2, -goff)));
            buf_store_f32(xc[t % 4] * gt, osrd, og4, t * PLANE_B, 0);
        }
    });
}

}  // namespace

extern "C" void kernel_launch(void* const* d_in, const int* in_sizes, int n_in,
                              void* d_out, int out_size, void* d_ws, size_t ws_size,
                              hipStream_t stream) {
    (void)in_sizes; (void)n_in; (void)d_ws; (void)ws_size; (void)out_size;
    const float* x  = (const float*)d_in[0];
    const float* w1 = (const float*)d_in[1];
    const float* b1 = (const float*)d_in[2];
    const float* w2 = (const float*)d_in[3];
    const float* b2 = (const float*)d_in[4];
    const float* w3 = (const float*)d_in[5];
    const float* b3 = (const float*)d_in[6];
    const float* wm = (const float*)d_in[7];
    float* out = (float*)d_out;

    // grid: x = ceil(3136 px / 256) = 13, y = 256 (b,c); block = 256 (4 waves).
    // 1 px/thread streaming form; bc in blockIdx.y keeps weights scalar.
    tts_fused<<<dim3((HW + 255) / 256, 256), dim3(256), 0, stream>>>(
        x, w1, b1, w2, b2, w3, b3, wm, out);
}

// Round 5
// 293.621 us; speedup vs baseline: 2.8295x; 1.4497x over previous
//
#include <hip/hip_runtime.h>

namespace {

constexpr int T = 32, H = 56, W = 56;
constexpr int HW = H * W;
constexpr int THW = T * HW;
constexpr int GROUPS = H * (W / 2);   // 1568 two-pixel groups per (b,c) plane-stack

template <int N> struct ic { static constexpr int value = N; };

__device__ __forceinline__ float sigm(float x) {
    // 1/(1+e^-x); fast native exp + rcp (rel err ~1e-6, threshold is 1.9e-2)
    float e = __expf(-x);
    return __builtin_amdgcn_rcpf(1.0f + e);
}

// Geometry history on this problem (keep -- hard-won):
//   (64 thr, 1 wave/wg): wg-slot cap -> 27% occupancy, 140 us.      [R1 best]
//   (128,5)/(256,8) pins: cap < true live set (~84 + weights) ->
//       catastrophic scratch spill (0.5-2 GB traffic), 300-730 us.  [R2/R4]
// VGPR occupancy bins are power-of-2 (waves/SIMD halve at 64/128/256 VGPRs),
// so 84 VGPRs sits in the 4-wave bin regardless; (128,4) is the FEASIBLE pin:
// cap 128 >= 84 -> no spill, 2 waves/wg beats the wg-slot cap -> 50% ceiling.
__global__ __launch_bounds__(128, 4)
void tts_fused(const float* __restrict__ x,
               const float* __restrict__ w1, const float* __restrict__ b1,
               const float* __restrict__ w2, const float* __restrict__ b2,
               const float* __restrict__ w3, const float* __restrict__ b3,
               const float* __restrict__ wm,
               float* __restrict__ out) {
    // blockIdx.y = (b*64 + c)  -> block-uniform so weight loads stay scalar.
    // blockIdx.x * 128 + tid   -> linear 2-pixel group within the 56x56 plane.
    const int g = blockIdx.x * 128 + threadIdx.x;
    if (g >= GROUPS) return;          // no barriers anywhere -> safe early exit
    const int bc = blockIdx.y;
    const int h  = g / 28;            // 0..55
    const int wq = g - h * 28;        // 0..27
    const int w0 = wq << 1;           // 2 pixels per thread, 8B-aligned

    const float* __restrict__ xbc = x + (size_t)bc * THW;
    float* __restrict__ obc       = out + (size_t)bc * THW;
    const int c = bc & 63;
    const float* __restrict__ wa = w1 + c * 27;  // [kt*9 + kh*3 + kw]
    const float* __restrict__ wb = w2 + c * 27;
    const float* __restrict__ wc = w3 + c * 27;
    const float bias1 = b1[c], bias2 = b2[c], bias3 = b3[c];
    const float W0 = wm[0], W1 = wm[1], W2 = wm[2];
    const float goff = 0.5f * (W0 + W1 + W2);

    const bool vtop = (h >= 1), vbot = (h <= H - 2);
    const bool vl = (wq > 0), vr = (wq < 27);
    const int boff = h * W + w0;

    // register cache: 7 planes (t-3..t+3, slot = plane mod 7) x 3 rows x 4 cols (w0-1..w0+2)
    float cc[7][3][4];
    // lag-diff shift registers per pixel
    float p1[2], p2a[2], p2b[2], p3a[2], p3b[2], p3c[2];
#pragma unroll
    for (int p = 0; p < 2; ++p) {
        p1[p] = 0.f; p2a[p] = 0.f; p2b[p] = 0.f;
        p3a[p] = 0.f; p3b[p] = 0.f; p3c[p] = 0.f;
    }

    auto zero_plane = [&](auto Sc) {
        constexpr int s = decltype(Sc)::value;
#pragma unroll
        for (int r = 0; r < 3; ++r)
#pragma unroll
            for (int j = 0; j < 4; ++j) cc[s][r][j] = 0.f;
    };

    auto load_plane = [&](auto Sc, int tp) {
        constexpr int s = decltype(Sc)::value;
        const float* pp = xbc + tp * HW + boff;
#pragma unroll
        for (int r = 0; r < 3; ++r) {
            const bool vrow = (r == 0) ? vtop : ((r == 2) ? vbot : true);
            const float* rp = pp + (r - 1) * W;
            if (vrow) {
                const float2 m = *(const float2*)rp;      // aligned: offset % 2 == 0
                cc[s][r][1] = m.x; cc[s][r][2] = m.y;
                cc[s][r][0] = vl ? rp[-1] : 0.f;
                cc[s][r][3] = vr ? rp[2]  : 0.f;
            } else {
#pragma unroll
                for (int j = 0; j < 4; ++j) cc[s][r][j] = 0.f;
            }
        }
    };

    auto conv9 = [&](float (&acc)[2], auto Sc, const float* __restrict__ wp) {
        constexpr int s = decltype(Sc)::value;
#pragma unroll
        for (int r = 0; r < 3; ++r)
#pragma unroll
            for (int kw = 0; kw < 3; ++kw) {
                const float wg = wp[r * 3 + kw];
#pragma unroll
                for (int p = 0; p < 2; ++p)
                    acc[p] = fmaf(cc[s][r][p + kw], wg, acc[p]);
            }
    };

    // prologue: planes -3..-1 are zero (slots 4,5,6); planes 0..2 loaded (slots 0,1,2)
    zero_plane(ic<4>{}); zero_plane(ic<5>{}); zero_plane(ic<6>{});
    load_plane(ic<0>{}, 0); load_plane(ic<1>{}, 1); load_plane(ic<2>{}, 2);

    auto step = [&](int t, auto Uc) {   // requires t % 7 == Uc
        constexpr int u = decltype(Uc)::value;
        constexpr int snew = (u + 3) % 7;               // slot of plane t+3
        if (t + 3 < T) load_plane(ic<snew>{}, t + 3);
        else           zero_plane(ic<snew>{});

        float a1[2], a2[2], a3[2];
#pragma unroll
        for (int p = 0; p < 2; ++p) { a1[p] = bias1; a2[p] = bias2; a3[p] = bias3; }

        conv9(a1, ic<(u + 6) % 7>{}, wa);       // plane t-1
        conv9(a1, ic<u>{},           wa + 9);   // plane t
        conv9(a1, ic<(u + 1) % 7>{}, wa + 18);  // plane t+1
        conv9(a2, ic<(u + 5) % 7>{}, wb);       // plane t-2
        conv9(a2, ic<u>{},           wb + 9);   // plane t
        conv9(a2, ic<(u + 2) % 7>{}, wb + 18);  // plane t+2
        conv9(a3, ic<(u + 4) % 7>{}, wc);       // plane t-3
        conv9(a3, ic<u>{},           wc + 9);   // plane t
        conv9(a3, ic<(u + 3) % 7>{}, wc + 18);  // plane t+3 (freshly loaded) LAST

        float2 ov;
        float* ovp = (float*)&ov;
#pragma unroll
        for (int p = 0; p < 2; ++p) {
            const float y1 = a1[p], y2 = a2[p], y3 = a3[p];
            const float d1 = (t >= 1) ? y1 - p1[p]  : y1;
            const float d2 = (t >= 2) ? y2 - p2b[p] : y2;
            const float d3 = (t >= 3) ? y3 - p3c[p] : y3;
            p1[p]  = y1;
            p2b[p] = p2a[p]; p2a[p] = y2;
            p3c[p] = p3b[p]; p3b[p] = p3a[p]; p3a[p] = y3;
            const float gte = fmaf(sigm(d1), W0,
                             fmaf(sigm(d2), W1,
                             fmaf(sigm(d3), W2, -goff)));
            ovp[p] = cc[u][1][p + 1] * gte;     // x at (t,h,w0+p) from register cache
        }
        *(float2*)(obc + t * HW + boff) = ov;
    };

#pragma unroll 1
    for (int tb = 0; tb <= T - 7; tb += 7) {    // tb = 0,7,14,21  (tb % 7 == 0)
        step(tb + 0, ic<0>{}); step(tb + 1, ic<1>{}); step(tb + 2, ic<2>{});
        step(tb + 3, ic<3>{}); step(tb + 4, ic<4>{}); step(tb + 5, ic<5>{});
        step(tb + 6, ic<6>{});
    }
    // remainder: t = 28..31 (28 % 7 == 0)
    step(28, ic<0>{}); step(29, ic<1>{}); step(30, ic<2>{}); step(31, ic<3>{});
}

}  // namespace

extern "C" void kernel_launch(void* const* d_in, const int* in_sizes, int n_in,
                              void* d_out, int out_size, void* d_ws, size_t ws_size,
                              hipStream_t stream) {
    (void)in_sizes; (void)n_in; (void)d_ws; (void)ws_size; (void)out_size;
    const float* x  = (const float*)d_in[0];
    const float* w1 = (const float*)d_in[1];
    const float* b1 = (const float*)d_in[2];
    const float* w2 = (const float*)d_in[3];
    const float* b2 = (const float*)d_in[4];
    const float* w3 = (const float*)d_in[5];
    const float* b3 = (const float*)d_in[6];
    const float* wm = (const float*)d_in[7];
    float* out = (float*)d_out;

    // grid: x = ceil(1568 groups / 128) = 13, y = 256 (b,c) pairs; block: 2 waves.
    // 2-wave blocks lift the wg-slot-limited wave ceiling; bc in blockIdx.y
    // keeps weight/bias loads block-uniform -> scalar path.
    tts_fused<<<dim3((GROUPS + 127) / 128, 256), dim3(128), 0, stream>>>(
        x, w1, b1, w2, b2, w3, b3, wm, out);
}

// Round 6
// 276.805 us; speedup vs baseline: 3.0013x; 1.0607x over previous
//
#include <hip/hip_runtime.h>

namespace {

constexpr int T = 32, H = 56, W = 56;
constexpr int HW = H * W;
constexpr int THW = T * HW;
constexpr int GROUPS = H * (W / 2);   // 1568 two-pixel groups per (b,c) plane-stack

template <int N> struct ic { static constexpr int value = N; };

__device__ __forceinline__ float sigm(float x) {
    // 1/(1+e^-x); fast native exp + rcp (rel err ~1e-6, threshold is 1.9e-2)
    float e = __expf(-x);
    return __builtin_amdgcn_rcpf(1.0f + e);
}

// Geometry history on this problem (keep -- hard-won):
//   compiler VGPR budget = floor(256 / min_waves_arg), NOT 512/min_waves:
//     (64,3)->84ok  (128,4)->64 SPILL  (128,5)->48 SPILL  (128,6)->40 SPILL
//     (256,8)->32 SPILL.  Live set is ~84 floats (7-plane ring) => the ONLY
//     feasible pin is min_waves=3 (cap 85). Never pin >=4 on this kernel.
//   1-wave wgs hit the ~8 wg/CU slot cap (27% occ) -> need 2-wave wgs.
//   HW occupancy bins (waves halve at 64/128/256 VGPRs): 84 VGPR -> 4/SIMD
//   bin, so cap 85 loses no occupancy vs 128.
__global__ __launch_bounds__(128, 3)
void tts_fused(const float* __restrict__ x,
               const float* __restrict__ w1, const float* __restrict__ b1,
               const float* __restrict__ w2, const float* __restrict__ b2,
               const float* __restrict__ w3, const float* __restrict__ b3,
               const float* __restrict__ wm,
               float* __restrict__ out) {
    // blockIdx.y = (b*64 + c)  -> block-uniform so weight loads stay scalar.
    // blockIdx.x * 128 + tid   -> linear 2-pixel group within the 56x56 plane.
    const int g = blockIdx.x * 128 + threadIdx.x;
    if (g >= GROUPS) return;          // no barriers anywhere -> safe early exit
    const int bc = blockIdx.y;
    const int h  = g / 28;            // 0..55
    const int wq = g - h * 28;        // 0..27
    const int w0 = wq << 1;           // 2 pixels per thread, 8B-aligned

    const float* __restrict__ xbc = x + (size_t)bc * THW;
    float* __restrict__ obc       = out + (size_t)bc * THW;
    const int c = bc & 63;
    const float* __restrict__ wa = w1 + c * 27;  // [kt*9 + kh*3 + kw]
    const float* __restrict__ wb = w2 + c * 27;
    const float* __restrict__ wc = w3 + c * 27;
    const float bias1 = b1[c], bias2 = b2[c], bias3 = b3[c];
    const float W0 = wm[0], W1 = wm[1], W2 = wm[2];
    const float goff = 0.5f * (W0 + W1 + W2);

    const bool vtop = (h >= 1), vbot = (h <= H - 2);
    const bool vl = (wq > 0), vr = (wq < 27);
    const int boff = h * W + w0;

    // register cache: 7 planes (t-3..t+3, slot = plane mod 7) x 3 rows x 4 cols (w0-1..w0+2)
    float cc[7][3][4];
    // lag-diff shift registers per pixel
    float p1[2], p2a[2], p2b[2], p3a[2], p3b[2], p3c[2];
#pragma unroll
    for (int p = 0; p < 2; ++p) {
        p1[p] = 0.f; p2a[p] = 0.f; p2b[p] = 0.f;
        p3a[p] = 0.f; p3b[p] = 0.f; p3c[p] = 0.f;
    }

    auto zero_plane = [&](auto Sc) {
        constexpr int s = decltype(Sc)::value;
#pragma unroll
        for (int r = 0; r < 3; ++r)
#pragma unroll
            for (int j = 0; j < 4; ++j) cc[s][r][j] = 0.f;
    };

    auto load_plane = [&](auto Sc, int tp) {
        constexpr int s = decltype(Sc)::value;
        const float* pp = xbc + tp * HW + boff;
#pragma unroll
        for (int r = 0; r < 3; ++r) {
            const bool vrow = (r == 0) ? vtop : ((r == 2) ? vbot : true);
            const float* rp = pp + (r - 1) * W;
            if (vrow) {
                const float2 m = *(const float2*)rp;      // aligned: offset % 2 == 0
                cc[s][r][1] = m.x; cc[s][r][2] = m.y;
                cc[s][r][0] = vl ? rp[-1] : 0.f;
                cc[s][r][3] = vr ? rp[2]  : 0.f;
            } else {
#pragma unroll
                for (int j = 0; j < 4; ++j) cc[s][r][j] = 0.f;
            }
        }
    };

    auto conv9 = [&](float (&acc)[2], auto Sc, const float* __restrict__ wp) {
        constexpr int s = decltype(Sc)::value;
#pragma unroll
        for (int r = 0; r < 3; ++r)
#pragma unroll
            for (int kw = 0; kw < 3; ++kw) {
                const float wg = wp[r * 3 + kw];
#pragma unroll
                for (int p = 0; p < 2; ++p)
                    acc[p] = fmaf(cc[s][r][p + kw], wg, acc[p]);
            }
    };

    // prologue: planes -3..-1 are zero (slots 4,5,6); planes 0..2 loaded (slots 0,1,2)
    zero_plane(ic<4>{}); zero_plane(ic<5>{}); zero_plane(ic<6>{});
    load_plane(ic<0>{}, 0); load_plane(ic<1>{}, 1); load_plane(ic<2>{}, 2);

    auto step = [&](int t, auto Uc) {   // requires t % 7 == Uc
        constexpr int u = decltype(Uc)::value;
        constexpr int snew = (u + 3) % 7;               // slot of plane t+3
        if (t + 3 < T) load_plane(ic<snew>{}, t + 3);
        else           zero_plane(ic<snew>{});

        float a1[2], a2[2], a3[2];
#pragma unroll
        for (int p = 0; p < 2; ++p) { a1[p] = bias1; a2[p] = bias2; a3[p] = bias3; }

        conv9(a1, ic<(u + 6) % 7>{}, wa);       // plane t-1
        conv9(a1, ic<u>{},           wa + 9);   // plane t
        conv9(a1, ic<(u + 1) % 7>{}, wa + 18);  // plane t+1
        conv9(a2, ic<(u + 5) % 7>{}, wb);       // plane t-2
        conv9(a2, ic<u>{},           wb + 9);   // plane t
        conv9(a2, ic<(u + 2) % 7>{}, wb + 18);  // plane t+2
        conv9(a3, ic<(u + 4) % 7>{}, wc);       // plane t-3
        conv9(a3, ic<u>{},           wc + 9);   // plane t
        conv9(a3, ic<(u + 3) % 7>{}, wc + 18);  // plane t+3 (freshly loaded) LAST

        float2 ov;
        float* ovp = (float*)&ov;
#pragma unroll
        for (int p = 0; p < 2; ++p) {
            const float y1 = a1[p], y2 = a2[p], y3 = a3[p];
            const float d1 = (t >= 1) ? y1 - p1[p]  : y1;
            const float d2 = (t >= 2) ? y2 - p2b[p] : y2;
            const float d3 = (t >= 3) ? y3 - p3c[p] : y3;
            p1[p]  = y1;
            p2b[p] = p2a[p]; p2a[p] = y2;
            p3c[p] = p3b[p]; p3b[p] = p3a[p]; p3a[p] = y3;
            const float gte = fmaf(sigm(d1), W0,
                             fmaf(sigm(d2), W1,
                             fmaf(sigm(d3), W2, -goff)));
            ovp[p] = cc[u][1][p + 1] * gte;     // x at (t,h,w0+p) from register cache
        }
        *(float2*)(obc + t * HW + boff) = ov;
    };

#pragma unroll 1
    for (int tb = 0; tb <= T - 7; tb += 7) {    // tb = 0,7,14,21  (tb % 7 == 0)
        step(tb + 0, ic<0>{}); step(tb + 1, ic<1>{}); step(tb + 2, ic<2>{});
        step(tb + 3, ic<3>{}); step(tb + 4, ic<4>{}); step(tb + 5, ic<5>{});
        step(tb + 6, ic<6>{});
    }
    // remainder: t = 28..31 (28 % 7 == 0)
    step(28, ic<0>{}); step(29, ic<1>{}); step(30, ic<2>{}); step(31, ic<3>{});
}

}  // namespace

extern "C" void kernel_launch(void* const* d_in, const int* in_sizes, int n_in,
                              void* d_out, int out_size, void* d_ws, size_t ws_size,
                              hipStream_t stream) {
    (void)in_sizes; (void)n_in; (void)d_ws; (void)ws_size; (void)out_size;
    const float* x  = (const float*)d_in[0];
    const float* w1 = (const float*)d_in[1];
    const float* b1 = (const float*)d_in[2];
    const float* w2 = (const float*)d_in[3];
    const float* b2 = (const float*)d_in[4];
    const float* w3 = (const float*)d_in[5];
    const float* b3 = (const float*)d_in[6];
    const float* wm = (const float*)d_in[7];
    float* out = (float*)d_out;

    // grid: x = ceil(1568 groups / 128) = 13, y = 256 (b,c) pairs; block: 2 waves.
    // 2-wave blocks lift the ~8-wg/CU slot cap (1-wave wgs stuck at 27% occ);
    // bc in blockIdx.y keeps weight/bias loads block-uniform -> scalar path.
    tts_fused<<<dim3((GROUPS + 127) / 128, 256), dim3(128), 0, stream>>>(
        x, w1, b1, w2, b2, w3, b3, wm, out);
}